// Round 15
// baseline (99.998 us; speedup 1.0000x reference)
//
#include <hip/hip_runtime.h>
#include <math.h>

// Problem constants
#define B 16
#define H 1024
#define W 1024
#define TOPK 5000
#define SCORES_TH 0.2f

// selection pipeline constants
#define CAP 65536          // max candidates per batch (expected ~42k)
#define SELCAP 8192        // max selected per batch
#define NB2 9831           // buckets over value bits[31:11]
#define OFFB2 510361       // bits(0.2f) >> 11
#define GS2 9840           // padded per-batch stride for G (>= NB2+1)
#define SCHUNK 10          // ceil(NB2/1024)
#define CSTRIDE 32         // counts padded 128 B apart

// wave-NMS geometry (R15: SROWS 32 -> 16, 2x waves for latency hiding)
#define XSTRIPS 9          // ceil(1024/124)
#define YSTRIPS 64
#define SROWS 16           // output rows per wave
#define SCOLS 124          // output cols per wave (64 lanes x 2 - 4 halo)
#define WCAP 224           // per-wave LDS key buffer (expected ~79/strip)

// ---------------------------------------------------------------------------
// K1: wave-synchronous single 5x5 NMS (== double NMS, proven identity).
// No __syncthreads, no tile LDS. Each wave streams a 124x16 strip:
// per row: float2 load, shared pair-max + 4 shfls -> horizontal 5-max,
// 5-deep register ring -> vertical 5-max, peak==center test, emit to
// per-wave LDS buffer; one global atomic per wave at flush.
// Keys: (value_bits << 32) | ~idx  (desc value, asc index) — unique per pixel.
// ---------------------------------------------------------------------------
__global__ __launch_bounds__(256) void nms_wave(
    const float* __restrict__ s,
    unsigned* __restrict__ counts,
    unsigned long long* __restrict__ cand)
{
    __shared__ unsigned long long wbuf[4][WCAP];   // 7 KB, wave-private slices
    __shared__ unsigned wcnt[4];

    const int tid  = threadIdx.x;
    const int w    = tid >> 6;                     // wave within block
    const int lane = tid & 63;
    const int gw   = blockIdx.x * 4 + w;           // 0 .. 9215
    const int xs   = gw % XSTRIPS;
    const int t    = gw / XSTRIPS;                 // 0 .. 1023
    const int ys   = t & 63;
    const int b    = t >> 6;

    if (lane == 0) wcnt[w] = 0;

    const float* sb = s + (size_t)b * (H * W);
    const int c0 = xs * SCOLS - 2 + 2 * lane;      // this lane's first col
    const int y0 = ys * SROWS;
    const bool in0  = (c0 >= 0) & (c0 < W);
    const bool in1  = (c0 + 1 >= 0) & (c0 + 1 < W);
    const bool fast = in0 & in1;                   // float2 path (interior strips)
    const bool emitlane = (lane >= 1) & (lane <= 62);

    // vertical rings (named regs only — no runtime indexing)
    float ha0 = -INFINITY, ha1 = -INFINITY, ha2 = -INFINITY, ha3 = -INFINITY;
    float hb0 = -INFINITY, hb1 = -INFINITY, hb2 = -INFINITY, hb3 = -INFINITY;
    float va1 = -INFINITY, va2 = -INFINITY;        // center history (1-back, 2-back)
    float vb1 = -INFINITY, vb2 = -INFINITY;

    #pragma unroll 4
    for (int gy = y0 - 2; gy <= y0 + SROWS + 1; ++gy) {
        // ---- load row ------------------------------------------------------
        float a, bq;
        const bool yin = (gy >= 0) & (gy < H);
        if (yin & fast) {
            float2 v = *(const float2*)(sb + (size_t)gy * W + c0);
            a = v.x; bq = v.y;
        } else {
            a  = (yin & in0) ? sb[(size_t)gy * W + c0]     : -INFINITY;
            bq = (yin & in1) ? sb[(size_t)gy * W + c0 + 1] : -INFINITY;
        }

        // ---- horizontal 5-max via shfl -------------------------------------
        float p   = fmaxf(a, bq);
        float pm1 = __shfl_up(p, 1);               // p[l-1]
        float pp1 = __shfl_down(p, 1);             // p[l+1]
        float ap1 = __shfl_down(a, 1);             // a[l+1]
        float bm1 = __shfl_up(bq, 1);              // b[l-1]
        float hma = fmaxf(fmaxf(pm1, p), ap1);     // 5-max centered at c0
        float hmb = fmaxf(fmaxf(bm1, p), pp1);     // 5-max centered at c0+1

        // ---- emit output row r = gy-2 --------------------------------------
        if (gy >= y0 + 2) {
            float vma = fmaxf(fmaxf(fmaxf(ha0, ha1), fmaxf(ha2, ha3)), hma);
            float vmb = fmaxf(fmaxf(fmaxf(hb0, hb1), fmaxf(hb2, hb3)), hmb);
            bool pka = emitlane & in0 & (va2 > SCORES_TH) & (va2 == vma);
            bool pkb = emitlane & in1 & (vb2 > SCORES_TH) & (vb2 == vmb);
            if (pka | pkb) {
                int r = gy - 2;
                if (pka) {
                    unsigned idx = (unsigned)(r * W + c0);
                    unsigned long long key =
                        ((unsigned long long)__float_as_uint(va2) << 32) | (unsigned)(~idx);
                    unsigned pi = atomicAdd(&wcnt[w], 1u);
                    if (pi < WCAP) wbuf[w][pi] = key;
                    else {                          // overflow: direct reserved write
                        unsigned gp = atomicAdd(&counts[b * CSTRIDE], 1u);
                        if (gp < CAP) cand[(size_t)b * CAP + gp] = key;
                    }
                }
                if (pkb) {
                    unsigned idx = (unsigned)(r * W + c0 + 1);
                    unsigned long long key =
                        ((unsigned long long)__float_as_uint(vb2) << 32) | (unsigned)(~idx);
                    unsigned pi = atomicAdd(&wcnt[w], 1u);
                    if (pi < WCAP) wbuf[w][pi] = key;
                    else {
                        unsigned gp = atomicAdd(&counts[b * CSTRIDE], 1u);
                        if (gp < CAP) cand[(size_t)b * CAP + gp] = key;
                    }
                }
            }
        }

        // ---- shift rings ----------------------------------------------------
        ha0 = ha1; ha1 = ha2; ha2 = ha3; ha3 = hma;
        hb0 = hb1; hb1 = hb2; hb2 = hb3; hb3 = hmb;
        va2 = va1; va1 = a;
        vb2 = vb1; vb1 = bq;
    }

    // ---- flush: one global atomic per wave, coalesced copy ------------------
    unsigned n = wcnt[w]; if (n > WCAP) n = WCAP;
    unsigned base = 0;
    if (lane == 0) base = atomicAdd(&counts[b * CSTRIDE], n);
    base = __shfl(base, 0);
    for (unsigned k = (unsigned)lane; k < n; k += 64)
        if (base + k < CAP) cand[(size_t)b * CAP + base + k] = wbuf[w][k];
}

// ---------------------------------------------------------------------------
// K2: fused LDS-histogram + suffix-sum scan + threshold + publish G + scatter
// (LDS cursors). One block per batch. FROZEN (round 13).
// I[bk] = #{keys in buckets >= bk}; segment of bucket bk = [I[bk+1], I[bk]).
// ---------------------------------------------------------------------------
__global__ __launch_bounds__(1024) void scan_scatter(
    const unsigned* __restrict__ counts,
    const unsigned long long* __restrict__ cand,
    unsigned* __restrict__ G,
    unsigned* __restrict__ selC,
    unsigned long long* __restrict__ sel)
{
    const int b = blockIdx.x;
    __shared__ unsigned I[NB2 + 1];   // 39.3 KB
    __shared__ unsigned csum[1024];
    __shared__ int Tsh;
    const int tid = threadIdx.x;

    for (int i = tid; i < NB2 + 1; i += 1024) I[i] = 0;
    if (tid == 0) Tsh = 0;
    __syncthreads();

    unsigned M = counts[b * CSTRIDE]; if (M > CAP) M = CAP;
    const unsigned long long* cb = cand + (size_t)b * CAP;

    for (unsigned i = tid; i < M; i += 1024) {
        unsigned bits = (unsigned)(cb[i] >> 32);
        int bk = (int)(bits >> 11) - OFFB2;
        bk = bk < 0 ? 0 : (bk > NB2 - 1 ? NB2 - 1 : bk);
        atomicAdd(&I[bk], 1u);
    }
    __syncthreads();

    unsigned local = 0;
    #pragma unroll
    for (int u = 0; u < SCHUNK; ++u) {
        int r = tid * SCHUNK + u;
        if (r < NB2) local += I[NB2 - 1 - r];
    }
    csum[tid] = local;
    __syncthreads();
    for (int off = 1; off < 1024; off <<= 1) {      // Hillis-Steele inclusive
        unsigned v = (tid >= off) ? csum[tid - off] : 0u;
        __syncthreads();
        csum[tid] += v;
        __syncthreads();
    }
    unsigned run = (tid == 0) ? 0u : csum[tid - 1];
    #pragma unroll
    for (int u = 0; u < SCHUNK; ++u) {
        int r = tid * SCHUNK + u;
        if (r < NB2) {
            int bk = NB2 - 1 - r;
            run += I[bk];
            I[bk] = run;          // I becomes inclusive suffix sum
        }
    }
    __syncthreads();

    int localT = -1;
    #pragma unroll
    for (int u = 0; u < SCHUNK; ++u) {
        int r = tid * SCHUNK + u;
        if (r < NB2) {
            int bk = NB2 - 1 - r;
            if (I[bk] >= TOPK && bk > localT) localT = bk;
        }
    }
    if (localT >= 0) atomicMax(&Tsh, localT);
    __syncthreads();
    const int T = Tsh;
    if (tid == 0) selC[b] = I[T];

    unsigned* Gb = G + (size_t)b * GS2;
    for (int i = tid; i < NB2 + 1; i += 1024) Gb[i] = I[i];
    __syncthreads();

    for (unsigned i = tid; i < M; i += 1024) {
        unsigned long long key = cb[i];
        unsigned bits = (unsigned)(key >> 32);
        int bk = (int)(bits >> 11) - OFFB2;
        bk = bk < 0 ? 0 : (bk > NB2 - 1 ? NB2 - 1 : bk);
        if (bk >= T) {
            unsigned p = atomicAdd(&I[bk + 1], 1u);   // LDS cursor
            if (p < SELCAP) sel[(size_t)b * SELCAP + p] = key;
        }
    }
}

// ---------------------------------------------------------------------------
// K3: two-level exact rank, 4 lanes/key + zero-fill of ranks [C, TOPK).
// FROZEN (round 13).
// ---------------------------------------------------------------------------
__global__ __launch_bounds__(256) void rank_refine(
    const float* __restrict__ s,
    const unsigned long long* __restrict__ sel,
    const unsigned* __restrict__ selC,
    const unsigned* __restrict__ G,
    float* __restrict__ out)
{
    const int b = blockIdx.y;
    unsigned C = selC[b]; if (C > SELCAP) C = SELCAP;
    const int tid = threadIdx.x;
    const unsigned g = blockIdx.x * 64u + (unsigned)(tid >> 2);
    const int l = tid & 3;

    if (g >= C) {                     // zero-fill unclaimed output ranks
        if (g < TOPK && l == 0) {
            out[((size_t)b * TOPK + g) * 2 + 0] = 0.0f;
            out[((size_t)b * TOPK + g) * 2 + 1] = 0.0f;
            out[(size_t)B * TOPK * 2 + (size_t)b * TOPK + g] = 0.0f;
        }
        return;
    }

    const unsigned long long* sb = sel + (size_t)b * SELCAP;
    const unsigned long long my = sb[g];
    unsigned bits = (unsigned)(my >> 32);
    int bk = (int)(bits >> 11) - OFFB2;
    bk = bk < 0 ? 0 : (bk > NB2 - 1 ? NB2 - 1 : bk);

    const unsigned* Gb = G + (size_t)b * GS2;
    unsigned start = Gb[bk + 1], end = Gb[bk];
    if (end > SELCAP) end = SELCAP;
    unsigned rank = 0;
    for (unsigned j = start + (unsigned)l; j < end; j += 4)
        rank += (sb[j] > my) ? 1u : 0u;

    float v = __uint_as_float(bits);
    unsigned idx = ~((unsigned)my);
    int y = (int)(idx >> 10), x = (int)(idx & 1023);
    const float* smb = s + (size_t)b * (H * W);
    float wsum = 0.f, ox = 0.f, oy = 0.f;
    for (int c = l; c < 25; c += 4) {
        int dy = c / 5 - 2, dx = c - (c / 5) * 5 - 2;
        int yy = y + dy, xx = x + dx;
        bool inb = (yy >= 0 && yy < H && xx >= 0 && xx < W);
        int yc = min(max(yy, 0), H - 1), xc = min(max(xx, 0), W - 1);
        float p = smb[yc * W + xc];
        float lg = inb ? p * 10.0f : -1e9f;   // 1/TEMPERATURE = 10
        float e = expf(lg);
        wsum += e; ox += e * (float)dx; oy += e * (float)dy;
    }
    rank += __shfl_xor(rank, 1); rank += __shfl_xor(rank, 2);
    wsum += __shfl_xor(wsum, 1); wsum += __shfl_xor(wsum, 2);
    ox   += __shfl_xor(ox, 1);   ox   += __shfl_xor(ox, 2);
    oy   += __shfl_xor(oy, 1);   oy   += __shfl_xor(oy, 2);

    unsigned frank = start + rank;
    if (l == 0 && frank < TOPK) {
        float offx = ox / wsum, offy = oy / wsum;
        out[((size_t)b * TOPK + frank) * 2 + 0] = (float)x + offx;
        out[((size_t)b * TOPK + frank) * 2 + 1] = (float)y + offy;
        out[(size_t)B * TOPK * 2 + (size_t)b * TOPK + frank] = v;
    }
}

// ---------------------------------------------------------------------------
extern "C" void kernel_launch(void* const* d_in, const int* in_sizes, int n_in,
                              void* d_out, int out_size, void* d_ws, size_t ws_size,
                              hipStream_t stream)
{
    const float* s = (const float*)d_in[0];
    float* out = (float*)d_out;
    char* ws = (char*)d_ws;

    size_t off = 0;
    unsigned* counts        = (unsigned*)(ws + off);  off += 2048;   // B*CSTRIDE*4
    unsigned* selC          = (unsigned*)(ws + off);  off += 64;
    unsigned* G             = (unsigned*)(ws + off);  off += (size_t)B * GS2 * 4;  // 630 KB
    unsigned long long* sel = (unsigned long long*)(ws + off); off += (size_t)B * SELCAP * 8; // 1 MB
    unsigned long long* cand= (unsigned long long*)(ws + off);                     // 8.4 MB

    hipMemsetAsync(counts, 0, 2048, stream);

    nms_wave<<<dim3(XSTRIPS * YSTRIPS * B / 4), dim3(256), 0, stream>>>(s, counts, cand);
    scan_scatter<<<dim3(B), dim3(1024), 0, stream>>>(counts, cand, G, selC, sel);
    rank_refine<<<dim3(SELCAP * 4 / 256, B), dim3(256), 0, stream>>>(s, sel, selC, G, out);
}

// Round 16
// 84.989 us; speedup vs baseline: 1.1766x; 1.1766x over previous
//
#include <hip/hip_runtime.h>
#include <math.h>

// Problem constants
#define B 16
#define H 1024
#define W 1024
#define TOPK 5000
#define SCORES_TH 0.2f

// selection pipeline constants
#define CAP 65536          // max candidates per batch (expected ~42k)
#define SELCAP 8192        // max selected per batch
#define NB2 9831           // buckets over value bits[31:11]
#define OFFB2 510361       // bits(0.2f) >> 11
#define GS2 9840           // padded per-batch stride for G (>= NB2+1)
#define SCHUNK 10          // ceil(NB2/1024)
#define CSTRIDE 32         // counts padded 128 B apart

// wave-NMS geometry (R16: float4 lanes — 4 cols/lane, 1 shfl/col)
#define XSTRIPS 5          // ceil(1024/252)
#define YSTRIPS 64
#define SROWS 16           // output rows per wave
#define SCOLS 252          // output cols per wave (64 lanes x 4 - 4 halo)
#define WCAP 224           // per-wave LDS key buffer (expected ~129/strip)

// ---------------------------------------------------------------------------
// K1: wave-synchronous single 5x5 NMS (== double NMS, proven identity).
// float4 per lane: 3 in-lane pair-maxes + 4 shfls yield the horizontal 5-max
// for 4 columns (1 shfl/col, was 2). 5-deep register ring -> vertical max.
// Lane-boundary shfl garbage only affects never-emitted columns (idx mask).
// Keys: (value_bits << 32) | ~idx  (desc value, asc index) — unique per pixel.
// ---------------------------------------------------------------------------
__global__ __launch_bounds__(256) void nms_wave(
    const float* __restrict__ s,
    unsigned* __restrict__ counts,
    unsigned long long* __restrict__ cand)
{
    __shared__ unsigned long long wbuf[4][WCAP];   // 7 KB, wave-private slices
    __shared__ unsigned wcnt[4];

    const int tid  = threadIdx.x;
    const int w    = tid >> 6;                     // wave within block
    const int lane = tid & 63;
    const int gw   = blockIdx.x * 4 + w;           // 0 .. 5119
    const int xs   = gw % XSTRIPS;
    const int t    = gw / XSTRIPS;                 // 0 .. 1023
    const int ys   = t & (YSTRIPS - 1);
    const int b    = t >> 6;

    if (lane == 0) wcnt[w] = 0;

    const float* sb = s + (size_t)b * (H * W);
    const int c0 = xs * SCOLS - 2 + 4 * lane;      // lane's first col (dword-aligned)
    const int y0 = ys * SROWS;
    const bool wfast = (xs > 0) & (xs < XSTRIPS - 1);   // wave-uniform fast path

    bool inb[4], emitok[4];
    #pragma unroll
    for (int j = 0; j < 4; ++j) {
        int col = c0 + j, idx4 = 4 * lane + j;
        inb[j]    = (col >= 0) & (col < W);
        emitok[j] = inb[j] & (idx4 >= 2) & (idx4 <= 253);
    }

    float ring[4][4], p1[4], p2[4];
    #pragma unroll
    for (int j = 0; j < 4; ++j) {
        ring[j][0] = ring[j][1] = ring[j][2] = ring[j][3] = -INFINITY;
        p1[j] = p2[j] = -INFINITY;
    }

    #pragma unroll 4
    for (int gy = y0 - 2; gy <= y0 + SROWS + 1; ++gy) {
        // ---- load row ------------------------------------------------------
        float a[4];
        const bool yin = (gy >= 0) & (gy < H);
        if (yin & wfast) {
            float4 v = *(const float4*)(sb + (size_t)gy * W + c0);
            a[0] = v.x; a[1] = v.y; a[2] = v.z; a[3] = v.w;
        } else if (yin) {
            #pragma unroll
            for (int j = 0; j < 4; ++j)
                a[j] = inb[j] ? sb[(size_t)gy * W + c0 + j] : -INFINITY;
        } else {
            #pragma unroll
            for (int j = 0; j < 4; ++j) a[j] = -INFINITY;
        }

        // ---- horizontal 5-max: 3 pair-maxes + 4 shfls for 4 cols -----------
        float pm01 = fmaxf(a[0], a[1]);
        float pm12 = fmaxf(a[1], a[2]);
        float pm23 = fmaxf(a[2], a[3]);
        float Lh  = __shfl_up(pm23, 1);            // cols c0-2,c0-1
        float La3 = __shfl_up(a[3], 1);            // col  c0-1
        float Ra0 = __shfl_down(a[0], 1);          // col  c0+4
        float Rp  = __shfl_down(pm01, 1);          // cols c0+4,c0+5
        float h[4];
        h[0] = fmaxf(fmaxf(Lh,  pm01), a[2]);      // c0-2..c0+2
        h[1] = fmaxf(fmaxf(La3, pm01), pm23);      // c0-1..c0+3
        h[2] = fmaxf(fmaxf(pm01, pm23), Ra0);      // c0  ..c0+4
        h[3] = fmaxf(fmaxf(pm12, pm23), Rp);       // c0+1..c0+5

        // ---- emit output row r = gy-2 --------------------------------------
        if (gy >= y0 + 2) {
            const int r = gy - 2;
            #pragma unroll
            for (int j = 0; j < 4; ++j) {
                float vm = fmaxf(fmaxf(fmaxf(ring[j][0], ring[j][1]),
                                       fmaxf(ring[j][2], ring[j][3])), h[j]);
                bool pk = emitok[j] & (p2[j] > SCORES_TH) & (p2[j] == vm);
                if (pk) {
                    unsigned idx = (unsigned)(r * W + c0 + j);
                    unsigned long long key =
                        ((unsigned long long)__float_as_uint(p2[j]) << 32) | (unsigned)(~idx);
                    unsigned pi = atomicAdd(&wcnt[w], 1u);
                    if (pi < WCAP) wbuf[w][pi] = key;
                    else {                          // overflow: direct reserved write
                        unsigned gp = atomicAdd(&counts[b * CSTRIDE], 1u);
                        if (gp < CAP) cand[(size_t)b * CAP + gp] = key;
                    }
                }
            }
        }

        // ---- shift rings (renamed by unroll) --------------------------------
        #pragma unroll
        for (int j = 0; j < 4; ++j) {
            ring[j][0] = ring[j][1]; ring[j][1] = ring[j][2];
            ring[j][2] = ring[j][3]; ring[j][3] = h[j];
            p2[j] = p1[j]; p1[j] = a[j];
        }
    }

    // ---- flush: one global atomic per wave, coalesced copy ------------------
    unsigned n = wcnt[w]; if (n > WCAP) n = WCAP;
    unsigned base = 0;
    if (lane == 0) base = atomicAdd(&counts[b * CSTRIDE], n);
    base = __shfl(base, 0);
    for (unsigned k = (unsigned)lane; k < n; k += 64)
        if (base + k < CAP) cand[(size_t)b * CAP + base + k] = wbuf[w][k];
}

// ---------------------------------------------------------------------------
// K2: fused LDS-histogram + suffix-sum scan + threshold + publish G + scatter
// (LDS cursors). One block per batch. FROZEN (round 13).
// I[bk] = #{keys in buckets >= bk}; segment of bucket bk = [I[bk+1], I[bk]).
// ---------------------------------------------------------------------------
__global__ __launch_bounds__(1024) void scan_scatter(
    const unsigned* __restrict__ counts,
    const unsigned long long* __restrict__ cand,
    unsigned* __restrict__ G,
    unsigned* __restrict__ selC,
    unsigned long long* __restrict__ sel)
{
    const int b = blockIdx.x;
    __shared__ unsigned I[NB2 + 1];   // 39.3 KB
    __shared__ unsigned csum[1024];
    __shared__ int Tsh;
    const int tid = threadIdx.x;

    for (int i = tid; i < NB2 + 1; i += 1024) I[i] = 0;
    if (tid == 0) Tsh = 0;
    __syncthreads();

    unsigned M = counts[b * CSTRIDE]; if (M > CAP) M = CAP;
    const unsigned long long* cb = cand + (size_t)b * CAP;

    for (unsigned i = tid; i < M; i += 1024) {
        unsigned bits = (unsigned)(cb[i] >> 32);
        int bk = (int)(bits >> 11) - OFFB2;
        bk = bk < 0 ? 0 : (bk > NB2 - 1 ? NB2 - 1 : bk);
        atomicAdd(&I[bk], 1u);
    }
    __syncthreads();

    unsigned local = 0;
    #pragma unroll
    for (int u = 0; u < SCHUNK; ++u) {
        int r = tid * SCHUNK + u;
        if (r < NB2) local += I[NB2 - 1 - r];
    }
    csum[tid] = local;
    __syncthreads();
    for (int off = 1; off < 1024; off <<= 1) {      // Hillis-Steele inclusive
        unsigned v = (tid >= off) ? csum[tid - off] : 0u;
        __syncthreads();
        csum[tid] += v;
        __syncthreads();
    }
    unsigned run = (tid == 0) ? 0u : csum[tid - 1];
    #pragma unroll
    for (int u = 0; u < SCHUNK; ++u) {
        int r = tid * SCHUNK + u;
        if (r < NB2) {
            int bk = NB2 - 1 - r;
            run += I[bk];
            I[bk] = run;          // I becomes inclusive suffix sum
        }
    }
    __syncthreads();

    int localT = -1;
    #pragma unroll
    for (int u = 0; u < SCHUNK; ++u) {
        int r = tid * SCHUNK + u;
        if (r < NB2) {
            int bk = NB2 - 1 - r;
            if (I[bk] >= TOPK && bk > localT) localT = bk;
        }
    }
    if (localT >= 0) atomicMax(&Tsh, localT);
    __syncthreads();
    const int T = Tsh;
    if (tid == 0) selC[b] = I[T];

    unsigned* Gb = G + (size_t)b * GS2;
    for (int i = tid; i < NB2 + 1; i += 1024) Gb[i] = I[i];
    __syncthreads();

    for (unsigned i = tid; i < M; i += 1024) {
        unsigned long long key = cb[i];
        unsigned bits = (unsigned)(key >> 32);
        int bk = (int)(bits >> 11) - OFFB2;
        bk = bk < 0 ? 0 : (bk > NB2 - 1 ? NB2 - 1 : bk);
        if (bk >= T) {
            unsigned p = atomicAdd(&I[bk + 1], 1u);   // LDS cursor
            if (p < SELCAP) sel[(size_t)b * SELCAP + p] = key;
        }
    }
}

// ---------------------------------------------------------------------------
// K3: two-level exact rank, 4 lanes/key + zero-fill of ranks [C, TOPK).
// FROZEN (round 13).
// ---------------------------------------------------------------------------
__global__ __launch_bounds__(256) void rank_refine(
    const float* __restrict__ s,
    const unsigned long long* __restrict__ sel,
    const unsigned* __restrict__ selC,
    const unsigned* __restrict__ G,
    float* __restrict__ out)
{
    const int b = blockIdx.y;
    unsigned C = selC[b]; if (C > SELCAP) C = SELCAP;
    const int tid = threadIdx.x;
    const unsigned g = blockIdx.x * 64u + (unsigned)(tid >> 2);
    const int l = tid & 3;

    if (g >= C) {                     // zero-fill unclaimed output ranks
        if (g < TOPK && l == 0) {
            out[((size_t)b * TOPK + g) * 2 + 0] = 0.0f;
            out[((size_t)b * TOPK + g) * 2 + 1] = 0.0f;
            out[(size_t)B * TOPK * 2 + (size_t)b * TOPK + g] = 0.0f;
        }
        return;
    }

    const unsigned long long* sb = sel + (size_t)b * SELCAP;
    const unsigned long long my = sb[g];
    unsigned bits = (unsigned)(my >> 32);
    int bk = (int)(bits >> 11) - OFFB2;
    bk = bk < 0 ? 0 : (bk > NB2 - 1 ? NB2 - 1 : bk);

    const unsigned* Gb = G + (size_t)b * GS2;
    unsigned start = Gb[bk + 1], end = Gb[bk];
    if (end > SELCAP) end = SELCAP;
    unsigned rank = 0;
    for (unsigned j = start + (unsigned)l; j < end; j += 4)
        rank += (sb[j] > my) ? 1u : 0u;

    float v = __uint_as_float(bits);
    unsigned idx = ~((unsigned)my);
    int y = (int)(idx >> 10), x = (int)(idx & 1023);
    const float* smb = s + (size_t)b * (H * W);
    float wsum = 0.f, ox = 0.f, oy = 0.f;
    for (int c = l; c < 25; c += 4) {
        int dy = c / 5 - 2, dx = c - (c / 5) * 5 - 2;
        int yy = y + dy, xx = x + dx;
        bool inb = (yy >= 0 && yy < H && xx >= 0 && xx < W);
        int yc = min(max(yy, 0), H - 1), xc = min(max(xx, 0), W - 1);
        float p = smb[yc * W + xc];
        float lg = inb ? p * 10.0f : -1e9f;   // 1/TEMPERATURE = 10
        float e = expf(lg);
        wsum += e; ox += e * (float)dx; oy += e * (float)dy;
    }
    rank += __shfl_xor(rank, 1); rank += __shfl_xor(rank, 2);
    wsum += __shfl_xor(wsum, 1); wsum += __shfl_xor(wsum, 2);
    ox   += __shfl_xor(ox, 1);   ox   += __shfl_xor(ox, 2);
    oy   += __shfl_xor(oy, 1);   oy   += __shfl_xor(oy, 2);

    unsigned frank = start + rank;
    if (l == 0 && frank < TOPK) {
        float offx = ox / wsum, offy = oy / wsum;
        out[((size_t)b * TOPK + frank) * 2 + 0] = (float)x + offx;
        out[((size_t)b * TOPK + frank) * 2 + 1] = (float)y + offy;
        out[(size_t)B * TOPK * 2 + (size_t)b * TOPK + frank] = v;
    }
}

// ---------------------------------------------------------------------------
extern "C" void kernel_launch(void* const* d_in, const int* in_sizes, int n_in,
                              void* d_out, int out_size, void* d_ws, size_t ws_size,
                              hipStream_t stream)
{
    const float* s = (const float*)d_in[0];
    float* out = (float*)d_out;
    char* ws = (char*)d_ws;

    size_t off = 0;
    unsigned* counts        = (unsigned*)(ws + off);  off += 2048;   // B*CSTRIDE*4
    unsigned* selC          = (unsigned*)(ws + off);  off += 64;
    unsigned* G             = (unsigned*)(ws + off);  off += (size_t)B * GS2 * 4;  // 630 KB
    unsigned long long* sel = (unsigned long long*)(ws + off); off += (size_t)B * SELCAP * 8; // 1 MB
    unsigned long long* cand= (unsigned long long*)(ws + off);                     // 8.4 MB

    hipMemsetAsync(counts, 0, 2048, stream);

    nms_wave<<<dim3(XSTRIPS * YSTRIPS * B / 4), dim3(256), 0, stream>>>(s, counts, cand);
    scan_scatter<<<dim3(B), dim3(1024), 0, stream>>>(counts, cand, G, selC, sel);
    rank_refine<<<dim3(SELCAP * 4 / 256, B), dim3(256), 0, stream>>>(s, sel, selC, G, out);
}